// Round 1
// baseline (244.138 us; speedup 1.0000x reference)
//
#include <hip/hip_runtime.h>
#include <math.h>

typedef float v4f __attribute__((ext_vector_type(4)));
typedef short bf16x8 __attribute__((ext_vector_type(8)));

#define AS1 __attribute__((address_space(1)))
#define AS3 __attribute__((address_space(3)))

static constexpr int Bn = 8192;   // batch
static constexpr int Hn = 768;    // hidden

__device__ __forceinline__ short f32_to_bf16(float x) {
    union { float f; unsigned u; } v; v.f = x;
    unsigned r = (v.u + 0x7FFFu + ((v.u >> 16) & 1u)) >> 16;
    return (short)r;
}

// ---------------- fp32 -> bf16 conversion (vectorized by 4) ----------------
__global__ void cvt_f32_bf16(const float* __restrict__ src, short* __restrict__ dst, int n4) {
    int i = blockIdx.x * blockDim.x + threadIdx.x;
    if (i < n4) {
        float4 v = ((const float4*)src)[i];
        short4 o;
        o.x = f32_to_bf16(v.x); o.y = f32_to_bf16(v.y);
        o.z = f32_to_bf16(v.z); o.w = f32_to_bf16(v.w);
        ((short4*)dst)[i] = o;
    }
}

// ---------------- zero small accumulators ----------------
__global__ void zero_kernel(float* __restrict__ p, int n) {
    for (int i = threadIdx.x; i < n; i += blockDim.x) p[i] = 0.0f;
}

// ---------------- bf16 MFMA GEMM: C = A @ W^T (+bias, epilogue) ----------------
// A: [8192,768] bf16 row-major; W: [768,768] bf16 row-major ([n][k] -> B^T form)
// EPI 0: out = bf16(tanh(v));  EPI 1: out = v (fp32);  EPI 2: out = exp(-tanh(v)) fp32
template <int EPI>
__global__ void gemm_bt(const short* __restrict__ A, const short* __restrict__ W,
                        const float* __restrict__ bias, void* __restrict__ out) {
    constexpr int K = Hn;
    __shared__ __align__(16) short As[128 * 64];
    __shared__ __align__(16) short Ws[128 * 64];

    const int t = threadIdx.x;            // 0..255
    const int row0 = blockIdx.x * 128;
    const int col0 = blockIdx.y * 128;

    const int w = t >> 6, lane = t & 63;
    const int wm = w >> 1, wn = w & 1;    // 2x2 waves, 64x64 each
    const int lr = lane & 15, quad = lane >> 4;

    // staging map: thread t -> row rt (within 32-row issue), k-block bb; XOR swizzle
    const int rt = t >> 3;                // 0..31
    const int bb = t & 7;
    const int bsrc = bb ^ (rt & 7);       // LDS slot (r,b) holds global block b^(r&7)

    v4f acc[4][4] = {};

    for (int k0 = 0; k0 < K; k0 += 64) {
#pragma unroll
        for (int i = 0; i < 4; ++i) {
            const short* gA = A + (size_t)(row0 + i * 32 + rt) * K + k0 + bsrc * 8;
            const short* gW = W + (size_t)(col0 + i * 32 + rt) * K + k0 + bsrc * 8;
            __builtin_amdgcn_global_load_lds((AS1 void*)gA, (AS3 void*)&As[i * 2048 + t * 8], 16, 0, 0);
            __builtin_amdgcn_global_load_lds((AS1 void*)gW, (AS3 void*)&Ws[i * 2048 + t * 8], 16, 0, 0);
        }
        __syncthreads();
#pragma unroll
        for (int s = 0; s < 2; ++s) {
            const int kb = s * 4 + quad;
            bf16x8 af[4], bfr[4];
#pragma unroll
            for (int mt = 0; mt < 4; ++mt) {
                int m = wm * 64 + mt * 16 + lr;
                af[mt] = *(const bf16x8*)&As[m * 64 + ((kb ^ (m & 7)) << 3)];
            }
#pragma unroll
            for (int nt = 0; nt < 4; ++nt) {
                int n = wn * 64 + nt * 16 + lr;
                bfr[nt] = *(const bf16x8*)&Ws[n * 64 + ((kb ^ (n & 7)) << 3)];
            }
#pragma unroll
            for (int mt = 0; mt < 4; ++mt)
#pragma unroll
                for (int nt = 0; nt < 4; ++nt)
                    acc[mt][nt] = __builtin_amdgcn_mfma_f32_16x16x32_bf16(af[mt], bfr[nt], acc[mt][nt], 0, 0, 0);
        }
        __syncthreads();
    }

    // epilogue: C/D layout col=lane&15, row=quad*4+r
#pragma unroll
    for (int nt = 0; nt < 4; ++nt) {
        const int col = col0 + wn * 64 + nt * 16 + lr;
        const float bcol = bias[col];
#pragma unroll
        for (int mt = 0; mt < 4; ++mt) {
#pragma unroll
            for (int r = 0; r < 4; ++r) {
                const int row = row0 + wm * 64 + mt * 16 + quad * 4 + r;
                float v = acc[mt][nt][r] + bcol;
                if (EPI == 0) {
                    ((short*)out)[(size_t)row * Hn + col] = f32_to_bf16(tanhf(v));
                } else if (EPI == 1) {
                    ((float*)out)[(size_t)row * Hn + col] = v;
                } else {
                    ((float*)out)[(size_t)row * Hn + col] = expf(-tanhf(v));
                }
            }
        }
    }
}

// ---------------- column sums of mu and mu^2 ----------------
__global__ void colsum_kernel(const float* __restrict__ mu, float* __restrict__ cs,
                              float* __restrict__ cs2) {
    const int c = blockIdx.x * 128 + threadIdx.x;
    const int r0 = blockIdx.y * 128;
    float s = 0.f, s2 = 0.f;
    for (int i = 0; i < 128; ++i) {
        float v = mu[(size_t)(r0 + i) * Hn + c];
        s += v; s2 += v * v;
    }
    atomicAdd(&cs[c], s);
    atomicAdd(&cs2[c], s2);
}

// ---------------- final fused reduction ----------------
__global__ void final_reduce(const float* __restrict__ mu, const float* __restrict__ iv,
                             const float* __restrict__ mb, const float* __restrict__ cs,
                             const float* __restrict__ cs2, float* __restrict__ accum) {
    constexpr float invB = 1.0f / 8192.0f;
    const int tid = blockIdx.x * blockDim.x + threadIdx.x;
    const int stride = gridDim.x * blockDim.x;
    const int total4 = Bn * Hn / 4;
    float s0 = 0.f, s1 = 0.f;
    for (int i = tid; i < total4; i += stride) {
        const int c4 = i % (Hn / 4);
        float4 m4 = ((const float4*)mu)[i];
        float4 v4 = ((const float4*)iv)[i];
        float4 b4 = ((const float4*)mb)[i];
        float4 c1 = ((const float4*)cs)[c4];
        float4 c2 = ((const float4*)cs2)[c4];
        const float mm[4] = {c1.x, c1.y, c1.z, c1.w};
        const float ms[4] = {c2.x, c2.y, c2.z, c2.w};
        const float m_[4] = {m4.x, m4.y, m4.z, m4.w};
        const float v_[4] = {v4.x, v4.y, v4.z, v4.w};
        const float b_[4] = {b4.x, b4.y, b4.z, b4.w};
#pragma unroll
        for (int j = 0; j < 4; ++j) {
            float mean  = mm[j] * invB;
            float sqm   = ms[j] * invB;
            float d     = m_[j] - b_[j];
            float pos   = -0.5f * d * d * v_[j];
            float pq    = sqm - 2.f * m_[j] * mean + m_[j] * m_[j];
            float neg   = -0.5f * pq * v_[j];
            s0 += pos;
            s1 += pos - neg;
        }
    }
    // block reduce (4 waves of 64)
    const int lane = threadIdx.x & 63, w = threadIdx.x >> 6;
    for (int off = 32; off > 0; off >>= 1) {
        s0 += __shfl_down(s0, off);
        s1 += __shfl_down(s1, off);
    }
    __shared__ float r0[4], r1[4];
    if (lane == 0) { r0[w] = s0; r1[w] = s1; }
    __syncthreads();
    if (threadIdx.x == 0) {
        atomicAdd(&accum[0], r0[0] + r0[1] + r0[2] + r0[3]);
        atomicAdd(&accum[1], r1[0] + r1[1] + r1[2] + r1[3]);
    }
}

__global__ void finalize_kernel(const float* __restrict__ accum, float* __restrict__ out) {
    if (threadIdx.x == 0) {
        out[0] = accum[0] * (1.0f / 8192.0f);
        out[1] = accum[1] * (1.0f / 8192.0f);
    }
}

extern "C" void kernel_launch(void* const* d_in, const int* in_sizes, int n_in,
                              void* d_out, int out_size, void* d_ws, size_t ws_size,
                              hipStream_t stream) {
    const float* modal_a = (const float*)d_in[0];
    const float* modal_b = (const float*)d_in[1];
    const float* W1m = (const float*)d_in[2];
    const float* b1m = (const float*)d_in[3];
    const float* W2m = (const float*)d_in[4];
    const float* b2m = (const float*)d_in[5];
    const float* W1v = (const float*)d_in[6];
    const float* b1v = (const float*)d_in[7];
    const float* W2v = (const float*)d_in[8];
    const float* b2v = (const float*)d_in[9];
    float* out = (float*)d_out;

    char* ws = (char*)d_ws;
    constexpr size_t szAH = (size_t)Bn * Hn * 2;   // bf16 [B,H]
    constexpr size_t szW  = (size_t)Hn * Hn * 2;   // bf16 [H,H]
    constexpr size_t szMF = (size_t)Bn * Hn * 4;   // fp32 [B,H]
    short* A_bf   = (short*)(ws);
    short* h1m    = (short*)(ws + szAH);
    short* h1v    = (short*)(ws + 2 * szAH);
    short* W1m_bf = (short*)(ws + 3 * szAH);
    short* W2m_bf = (short*)(ws + 3 * szAH + szW);
    short* W1v_bf = (short*)(ws + 3 * szAH + 2 * szW);
    short* W2v_bf = (short*)(ws + 3 * szAH + 3 * szW);
    float* mu     = (float*)(ws + 3 * szAH + 4 * szW);
    float* iv     = (float*)(ws + 3 * szAH + 4 * szW + szMF);
    float* cs     = (float*)(ws + 3 * szAH + 4 * szW + 2 * szMF);
    float* cs2    = cs + Hn;
    float* accum  = cs2 + Hn;

    // 1. zero colsums + accum (1538 floats)
    zero_kernel<<<1, 256, 0, stream>>>(cs, 2 * Hn + 2);

    // 2. convert inputs to bf16
    {
        int n4 = Bn * Hn / 4;
        cvt_f32_bf16<<<(n4 + 255) / 256, 256, 0, stream>>>(modal_a, A_bf, n4);
        int w4 = Hn * Hn / 4;
        cvt_f32_bf16<<<(w4 + 255) / 256, 256, 0, stream>>>(W1m, W1m_bf, w4);
        cvt_f32_bf16<<<(w4 + 255) / 256, 256, 0, stream>>>(W2m, W2m_bf, w4);
        cvt_f32_bf16<<<(w4 + 255) / 256, 256, 0, stream>>>(W1v, W1v_bf, w4);
        cvt_f32_bf16<<<(w4 + 255) / 256, 256, 0, stream>>>(W2v, W2v_bf, w4);
    }

    // 3. layer-1 GEMMs: h = tanh(A @ W1^T + b1) -> bf16
    dim3 grid(Bn / 128, Hn / 128);
    gemm_bt<0><<<grid, 256, 0, stream>>>(A_bf, W1m_bf, b1m, h1m);
    gemm_bt<0><<<grid, 256, 0, stream>>>(A_bf, W1v_bf, b1v, h1v);

    // 4. layer-2 GEMMs: mu (fp32), inv_var = exp(-tanh(.)) (fp32)
    gemm_bt<1><<<grid, 256, 0, stream>>>(h1m, W2m_bf, b2m, mu);
    gemm_bt<2><<<grid, 256, 0, stream>>>(h1v, W2v_bf, b2v, iv);

    // 5. column sums of mu, mu^2
    colsum_kernel<<<dim3(Hn / 128, Bn / 128), 128, 0, stream>>>(mu, cs, cs2);

    // 6. fused final reduction
    final_reduce<<<768, 256, 0, stream>>>(mu, iv, modal_b, cs, cs2, accum);

    // 7. finalize scalars
    finalize_kernel<<<1, 64, 0, stream>>>(accum, out);
}

// Round 2
// 206.730 us; speedup vs baseline: 1.1809x; 1.1809x over previous
//
#include <hip/hip_runtime.h>
#include <math.h>

typedef float v4f __attribute__((ext_vector_type(4)));
typedef short bf16x8 __attribute__((ext_vector_type(8)));

#define AS1 __attribute__((address_space(1)))
#define AS3 __attribute__((address_space(3)))

static constexpr int Bn = 8192;   // batch
static constexpr int Hn = 768;    // hidden

__device__ __forceinline__ short f32_to_bf16(float x) {
    union { float f; unsigned u; } v; v.f = x;
    unsigned r = (v.u + 0x7FFFu + ((v.u >> 16) & 1u)) >> 16;
    return (short)r;
}

// ---------------- fused prep: zero accumulators + fp32->bf16 all 5 tensors ----------------
__global__ void prep_kernel(const float* __restrict__ A,
                            const float* __restrict__ W1m, const float* __restrict__ W2m,
                            const float* __restrict__ W1v, const float* __restrict__ W2v,
                            short* __restrict__ A_bf,
                            short* __restrict__ W1m_bf, short* __restrict__ W2m_bf,
                            short* __restrict__ W1v_bf, short* __restrict__ W2v_bf,
                            float* __restrict__ zbuf, int nzero) {
    const int tid = blockIdx.x * blockDim.x + threadIdx.x;
    if (tid < nzero) zbuf[tid] = 0.0f;
    constexpr int A4 = Bn * Hn / 4;   // 1572864
    constexpr int W4 = Hn * Hn / 4;   // 147456
    const int total = A4 + 4 * W4;
    const int stride = gridDim.x * blockDim.x;
    for (int i = tid; i < total; i += stride) {
        const float* s; short* d; int j;
        if (i < A4) { s = A; d = A_bf; j = i; }
        else {
            int k = i - A4; int w = k / W4; j = k - w * W4;
            s = (w == 0) ? W1m : (w == 1) ? W2m : (w == 2) ? W1v : W2v;
            d = (w == 0) ? W1m_bf : (w == 1) ? W2m_bf : (w == 2) ? W1v_bf : W2v_bf;
        }
        float4 v = ((const float4*)s)[j];
        short4 o;
        o.x = f32_to_bf16(v.x); o.y = f32_to_bf16(v.y);
        o.z = f32_to_bf16(v.z); o.w = f32_to_bf16(v.w);
        ((short4*)d)[j] = o;
    }
}

// ---------------- bf16 MFMA GEMM pair: blockIdx.z picks the (A,W,bias,out) set ----------------
// LAYER 1: out = bf16(tanh(v))  (both z)
// LAYER 2: z=0 -> mu = v (fp32) + column sums of mu, mu^2 via atomics
//          z=1 -> iv = exp(-tanh(v)) (fp32)
template <int LAYER>
__global__ void gemm_fused(const short* __restrict__ A0, const short* __restrict__ A1,
                           const short* __restrict__ Wa, const short* __restrict__ Wb,
                           const float* __restrict__ ba, const float* __restrict__ bb,
                           void* __restrict__ outa, void* __restrict__ outb,
                           float* __restrict__ cs, float* __restrict__ cs2) {
    constexpr int K = Hn;
    __shared__ __align__(16) short As[128 * 64];
    __shared__ __align__(16) short Ws[128 * 64];

    const int z = blockIdx.z;
    const short* A = (LAYER == 1) ? A0 : (z ? A1 : A0);
    const short* W = z ? Wb : Wa;
    const float* bias = z ? bb : ba;
    void* out = z ? outb : outa;

    const int t = threadIdx.x;            // 0..255
    const int row0 = blockIdx.x * 128;
    const int col0 = blockIdx.y * 128;

    const int w = t >> 6, lane = t & 63;
    const int wm = w >> 1, wn = w & 1;    // 2x2 waves, 64x64 each
    const int lr = lane & 15, quad = lane >> 4;

    // staging map: thread t -> row rt (within 32-row issue), k-block bb; XOR swizzle
    const int rt = t >> 3;                // 0..31
    const int bbk = t & 7;
    const int bsrc = bbk ^ (rt & 7);      // LDS slot (r,b) holds global block b^(r&7)

    v4f acc[4][4] = {};

    for (int k0 = 0; k0 < K; k0 += 64) {
#pragma unroll
        for (int i = 0; i < 4; ++i) {
            const short* gA = A + (size_t)(row0 + i * 32 + rt) * K + k0 + bsrc * 8;
            const short* gW = W + (size_t)(col0 + i * 32 + rt) * K + k0 + bsrc * 8;
            __builtin_amdgcn_global_load_lds((AS1 void*)gA, (AS3 void*)&As[i * 2048 + t * 8], 16, 0, 0);
            __builtin_amdgcn_global_load_lds((AS1 void*)gW, (AS3 void*)&Ws[i * 2048 + t * 8], 16, 0, 0);
        }
        __syncthreads();
#pragma unroll
        for (int s = 0; s < 2; ++s) {
            const int kb = s * 4 + quad;
            bf16x8 af[4], bfr[4];
#pragma unroll
            for (int mt = 0; mt < 4; ++mt) {
                int m = wm * 64 + mt * 16 + lr;
                af[mt] = *(const bf16x8*)&As[m * 64 + ((kb ^ (m & 7)) << 3)];
            }
#pragma unroll
            for (int nt = 0; nt < 4; ++nt) {
                int n = wn * 64 + nt * 16 + lr;
                bfr[nt] = *(const bf16x8*)&Ws[n * 64 + ((kb ^ (n & 7)) << 3)];
            }
#pragma unroll
            for (int mt = 0; mt < 4; ++mt)
#pragma unroll
                for (int nt = 0; nt < 4; ++nt)
                    acc[mt][nt] = __builtin_amdgcn_mfma_f32_16x16x32_bf16(af[mt], bfr[nt], acc[mt][nt], 0, 0, 0);
        }
        __syncthreads();
    }

    // epilogue: C/D layout col=lane&15, row=quad*4+r
#pragma unroll
    for (int nt = 0; nt < 4; ++nt) {
        const int col = col0 + wn * 64 + nt * 16 + lr;
        const float bcol = bias[col];
        float s1 = 0.f, s2 = 0.f;
#pragma unroll
        for (int mt = 0; mt < 4; ++mt) {
#pragma unroll
            for (int r = 0; r < 4; ++r) {
                const int row = row0 + wm * 64 + mt * 16 + quad * 4 + r;
                float v = acc[mt][nt][r] + bcol;
                if (LAYER == 1) {
                    ((short*)out)[(size_t)row * Hn + col] = f32_to_bf16(tanhf(v));
                } else if (LAYER == 2) {
                    if (z == 0) {
                        ((float*)out)[(size_t)row * Hn + col] = v;
                        s1 += v; s2 += v * v;
                    } else {
                        ((float*)out)[(size_t)row * Hn + col] = expf(-tanhf(v));
                    }
                }
            }
        }
        if (LAYER == 2 && z == 0) {
            // reduce across quads (lanes with same lr hold the same column)
            s1 += __shfl_xor(s1, 16); s1 += __shfl_xor(s1, 32);
            s2 += __shfl_xor(s2, 16); s2 += __shfl_xor(s2, 32);
            if (quad == 0) {
                atomicAdd(&cs[col], s1);
                atomicAdd(&cs2[col], s2);
            }
        }
    }
}

// ---------------- final fused reduction + last-block finalize ----------------
__global__ void final_reduce(const float* __restrict__ mu, const float* __restrict__ iv,
                             const float* __restrict__ mb, const float* __restrict__ cs,
                             const float* __restrict__ cs2, float* __restrict__ accum,
                             float* __restrict__ out) {
    constexpr float invB = 1.0f / 8192.0f;
    const int tid = blockIdx.x * blockDim.x + threadIdx.x;
    const int stride = gridDim.x * blockDim.x;
    const int total4 = Bn * Hn / 4;
    float s0 = 0.f, s1 = 0.f;
    for (int i = tid; i < total4; i += stride) {
        const int c4 = i % (Hn / 4);
        float4 m4 = ((const float4*)mu)[i];
        float4 v4 = ((const float4*)iv)[i];
        float4 b4 = ((const float4*)mb)[i];
        float4 c1 = ((const float4*)cs)[c4];
        float4 c2 = ((const float4*)cs2)[c4];
        const float mm[4] = {c1.x, c1.y, c1.z, c1.w};
        const float ms[4] = {c2.x, c2.y, c2.z, c2.w};
        const float m_[4] = {m4.x, m4.y, m4.z, m4.w};
        const float v_[4] = {v4.x, v4.y, v4.z, v4.w};
        const float b_[4] = {b4.x, b4.y, b4.z, b4.w};
#pragma unroll
        for (int j = 0; j < 4; ++j) {
            float mean  = mm[j] * invB;
            float sqm   = ms[j] * invB;
            float d     = m_[j] - b_[j];
            float pos   = -0.5f * d * d * v_[j];
            float pq    = sqm - 2.f * m_[j] * mean + m_[j] * m_[j];
            float neg   = -0.5f * pq * v_[j];
            s0 += pos;
            s1 += pos - neg;
        }
    }
    // block reduce (4 waves of 64)
    const int lane = threadIdx.x & 63, w = threadIdx.x >> 6;
    for (int off = 32; off > 0; off >>= 1) {
        s0 += __shfl_down(s0, off);
        s1 += __shfl_down(s1, off);
    }
    __shared__ float r0[4], r1[4];
    if (lane == 0) { r0[w] = s0; r1[w] = s1; }
    __syncthreads();
    if (threadIdx.x == 0) {
        atomicAdd(&accum[0], r0[0] + r0[1] + r0[2] + r0[3]);
        atomicAdd(&accum[1], r1[0] + r1[1] + r1[2] + r1[3]);
        __threadfence();
        unsigned old = atomicAdd((unsigned int*)&accum[3], 1u);
        if (old == gridDim.x - 1) {
            // device-scope RMW reads to get coherent values cross-XCD
            float a0 = atomicAdd(&accum[0], 0.0f);
            float a1 = atomicAdd(&accum[1], 0.0f);
            out[0] = a0 * invB;
            out[1] = a1 * invB;
        }
    }
}

extern "C" void kernel_launch(void* const* d_in, const int* in_sizes, int n_in,
                              void* d_out, int out_size, void* d_ws, size_t ws_size,
                              hipStream_t stream) {
    const float* modal_a = (const float*)d_in[0];
    const float* modal_b = (const float*)d_in[1];
    const float* W1m = (const float*)d_in[2];
    const float* b1m = (const float*)d_in[3];
    const float* W2m = (const float*)d_in[4];
    const float* b2m = (const float*)d_in[5];
    const float* W1v = (const float*)d_in[6];
    const float* b1v = (const float*)d_in[7];
    const float* W2v = (const float*)d_in[8];
    const float* b2v = (const float*)d_in[9];
    float* out = (float*)d_out;

    char* ws = (char*)d_ws;
    constexpr size_t szAH = (size_t)Bn * Hn * 2;   // bf16 [B,H]
    constexpr size_t szW  = (size_t)Hn * Hn * 2;   // bf16 [H,H]
    constexpr size_t szMF = (size_t)Bn * Hn * 4;   // fp32 [B,H]
    short* A_bf   = (short*)(ws);
    short* h1m    = (short*)(ws + szAH);
    short* h1v    = (short*)(ws + 2 * szAH);
    short* W1m_bf = (short*)(ws + 3 * szAH);
    short* W2m_bf = (short*)(ws + 3 * szAH + szW);
    short* W1v_bf = (short*)(ws + 3 * szAH + 2 * szW);
    short* W2v_bf = (short*)(ws + 3 * szAH + 3 * szW);
    float* mu     = (float*)(ws + 3 * szAH + 4 * szW);
    float* iv     = (float*)(ws + 3 * szAH + 4 * szW + szMF);
    float* cs     = (float*)(ws + 3 * szAH + 4 * szW + 2 * szMF);
    float* cs2    = cs + Hn;
    float* accum  = cs2 + Hn;   // [0]=pos_sum [1]=bound_sum [2]=pad [3]=ticket

    // 1. fused zero + convert (5 tensors, grid-stride)
    prep_kernel<<<1280, 256, 0, stream>>>(modal_a, W1m, W2m, W1v, W2v,
                                          A_bf, W1m_bf, W2m_bf, W1v_bf, W2v_bf,
                                          cs, 2 * Hn + 4);

    // 2. layer-1 GEMM pair (z=0: mu-branch, z=1: logvar-branch), 768 blocks
    dim3 grid(Bn / 128, Hn / 128, 2);
    gemm_fused<1><<<grid, 256, 0, stream>>>(A_bf, A_bf, W1m_bf, W1v_bf, b1m, b1v,
                                            h1m, h1v, nullptr, nullptr);

    // 3. layer-2 GEMM pair: z=0 -> mu (fp32) + colsums; z=1 -> inv_var
    gemm_fused<2><<<grid, 256, 0, stream>>>(h1m, h1v, W2m_bf, W2v_bf, b2m, b2v,
                                            mu, iv, cs, cs2);

    // 4. final fused reduction + finalize (last block writes out)
    final_reduce<<<768, 256, 0, stream>>>(mu, iv, modal_b, cs, cs2, accum, out);
}

// Round 3
// 197.297 us; speedup vs baseline: 1.2374x; 1.0478x over previous
//
#include <hip/hip_runtime.h>
#include <math.h>

typedef float v4f __attribute__((ext_vector_type(4)));
typedef short bf16x8 __attribute__((ext_vector_type(8)));

#define AS1 __attribute__((address_space(1)))
#define AS3 __attribute__((address_space(3)))

static constexpr int Bn = 8192;   // batch
static constexpr int Hn = 768;    // hidden
static constexpr float invB = 1.0f / 8192.0f;

__device__ __forceinline__ short f32_to_bf16(float x) {
    union { float f; unsigned u; } v; v.f = x;
    unsigned r = (v.u + 0x7FFFu + ((v.u >> 16) & 1u)) >> 16;
    return (short)r;
}

// tanh(x) = 1 - 2/(exp(2x)+1) -- v_exp_f32 + v_rcp_f32, ~5 inst vs ~25 for tanhf
__device__ __forceinline__ float fast_tanh(float x) {
    float xc = fminf(fmaxf(x, -15.0f), 15.0f);
    float e = __expf(2.0f * xc);
    float r = __builtin_amdgcn_rcpf(e + 1.0f);
    return 1.0f - 2.0f * r;
}

// ---------------- fused prep: zero accumulators + fp32->bf16 all 5 tensors ----------------
__global__ void prep_kernel(const float* __restrict__ A,
                            const float* __restrict__ W1m, const float* __restrict__ W2m,
                            const float* __restrict__ W1v, const float* __restrict__ W2v,
                            short* __restrict__ A_bf,
                            short* __restrict__ W1m_bf, short* __restrict__ W2m_bf,
                            short* __restrict__ W1v_bf, short* __restrict__ W2v_bf,
                            float* __restrict__ zbuf, int nzero) {
    const int tid = blockIdx.x * blockDim.x + threadIdx.x;
    if (tid < nzero) zbuf[tid] = 0.0f;
    constexpr int A4 = Bn * Hn / 4;
    constexpr int W4 = Hn * Hn / 4;
    const int total = A4 + 4 * W4;
    const int stride = gridDim.x * blockDim.x;
    for (int i = tid; i < total; i += stride) {
        const float* s; short* d; int j;
        if (i < A4) { s = A; d = A_bf; j = i; }
        else {
            int k = i - A4; int w = k / W4; j = k - w * W4;
            s = (w == 0) ? W1m : (w == 1) ? W2m : (w == 2) ? W1v : W2v;
            d = (w == 0) ? W1m_bf : (w == 1) ? W2m_bf : (w == 2) ? W1v_bf : W2v_bf;
        }
        float4 v = ((const float4*)s)[j];
        short4 o;
        o.x = f32_to_bf16(v.x); o.y = f32_to_bf16(v.y);
        o.z = f32_to_bf16(v.z); o.w = f32_to_bf16(v.w);
        ((short4*)d)[j] = o;
    }
}

// ---------------- branch-paired bf16 MFMA GEMM, 64x64 tile ----------------
// LAYER 1: both branches share A tile; out = bf16(tanh(v+bias)) for m and v.
// LAYER 2: Am=h1m, Av=h1v; epilogue computes mu, iv=exp(-tanh(.)) in-register,
//          accumulates pos/Q scalars + per-column {mu, mu^2, iv, iv*mu} sums.
template <int LAYER>
__launch_bounds__(256, 5)
__global__ void gemm_club(const short* __restrict__ Am_g, const short* __restrict__ Av_g,
                          const short* __restrict__ Wm_g, const short* __restrict__ Wv_g,
                          const float* __restrict__ bm, const float* __restrict__ bv,
                          short* __restrict__ outm, short* __restrict__ outv,
                          const float* __restrict__ mb,
                          float* __restrict__ cs, float* __restrict__ cs2,
                          float* __restrict__ siv, float* __restrict__ sivmu,
                          float* __restrict__ accum) {
    constexpr int K = Hn;
    constexpr int NSH = (LAYER == 1) ? 3 * 4096 : 4 * 4096;   // 24KB / 32KB
    __shared__ __align__(16) short smem[NSH];
    short* As_m = smem;
    short* As_v = (LAYER == 1) ? smem : smem + 4096;
    short* Ws_m = (LAYER == 1) ? smem + 4096 : smem + 8192;
    short* Ws_v = (LAYER == 1) ? smem + 8192 : smem + 12288;

    const int t = threadIdx.x;            // 0..255
    const int row0 = blockIdx.x * 64;
    const int col0 = blockIdx.y * 64;
    const int w = t >> 6, lane = t & 63;
    const int wm = w >> 1, wn = w & 1;    // 2x2 waves, 32x32 each
    const int lr = lane & 15, quad = lane >> 4;

    const int rt = t >> 3;                // 0..31
    const int bsrc = (t & 7) ^ (rt & 7);  // XOR-swizzled k-block source

    // incremental staging pointers (avoid per-iter 64-bit addr recompute)
    const short* pAm[2]; const short* pAv[2]; const short* pWm[2]; const short* pWv[2];
#pragma unroll
    for (int i = 0; i < 2; ++i) {
        pAm[i] = Am_g + (size_t)(row0 + i * 32 + rt) * K + bsrc * 8;
        pWm[i] = Wm_g + (size_t)(col0 + i * 32 + rt) * K + bsrc * 8;
        pWv[i] = Wv_g + (size_t)(col0 + i * 32 + rt) * K + bsrc * 8;
        pAv[i] = (LAYER == 2) ? (Av_g + (size_t)(row0 + i * 32 + rt) * K + bsrc * 8) : pAm[i];
    }

    v4f accm[2][2] = {}, accv[2][2] = {};

    for (int k0 = 0; k0 < K; k0 += 64) {
#pragma unroll
        for (int i = 0; i < 2; ++i) {
            __builtin_amdgcn_global_load_lds((AS1 void*)pAm[i], (AS3 void*)&As_m[i * 2048 + t * 8], 16, 0, 0);
            if (LAYER == 2)
                __builtin_amdgcn_global_load_lds((AS1 void*)pAv[i], (AS3 void*)&As_v[i * 2048 + t * 8], 16, 0, 0);
            __builtin_amdgcn_global_load_lds((AS1 void*)pWm[i], (AS3 void*)&Ws_m[i * 2048 + t * 8], 16, 0, 0);
            __builtin_amdgcn_global_load_lds((AS1 void*)pWv[i], (AS3 void*)&Ws_v[i * 2048 + t * 8], 16, 0, 0);
            pAm[i] += 64; pWm[i] += 64; pWv[i] += 64;
            if (LAYER == 2) pAv[i] += 64;
        }
        __syncthreads();
#pragma unroll
        for (int s = 0; s < 2; ++s) {
            const int kb = s * 4 + quad;
            bf16x8 am[2], av[2], bmf[2], bvf[2];
#pragma unroll
            for (int mt = 0; mt < 2; ++mt) {
                int m = wm * 32 + mt * 16 + lr;
                int off = m * 64 + ((kb ^ (m & 7)) << 3);
                am[mt] = *(const bf16x8*)&As_m[off];
                if (LAYER == 2) av[mt] = *(const bf16x8*)&As_v[off];
            }
#pragma unroll
            for (int nt = 0; nt < 2; ++nt) {
                int n = wn * 32 + nt * 16 + lr;
                int off = n * 64 + ((kb ^ (n & 7)) << 3);
                bmf[nt] = *(const bf16x8*)&Ws_m[off];
                bvf[nt] = *(const bf16x8*)&Ws_v[off];
            }
#pragma unroll
            for (int mt = 0; mt < 2; ++mt)
#pragma unroll
                for (int nt = 0; nt < 2; ++nt) {
                    accm[mt][nt] = __builtin_amdgcn_mfma_f32_16x16x32_bf16(am[mt], bmf[nt], accm[mt][nt], 0, 0, 0);
                    accv[mt][nt] = __builtin_amdgcn_mfma_f32_16x16x32_bf16(
                        (LAYER == 1) ? am[mt] : av[mt], bvf[nt], accv[mt][nt], 0, 0, 0);
                }
        }
        __syncthreads();
    }

    // ---------------- epilogue: C/D layout col=lane&15, row=quad*4+r ----------------
    if (LAYER == 1) {
#pragma unroll
        for (int nt = 0; nt < 2; ++nt) {
            const int col = col0 + wn * 32 + nt * 16 + lr;
            const float bmc = bm[col], bvc = bv[col];
#pragma unroll
            for (int mt = 0; mt < 2; ++mt) {
#pragma unroll
                for (int r = 0; r < 4; ++r) {
                    const int row = row0 + wm * 32 + mt * 16 + quad * 4 + r;
                    outm[(size_t)row * Hn + col] = f32_to_bf16(fast_tanh(accm[mt][nt][r] + bmc));
                    outv[(size_t)row * Hn + col] = f32_to_bf16(fast_tanh(accv[mt][nt][r] + bvc));
                }
            }
        }
    } else {
        float pos = 0.f, q = 0.f;   // pos = sum iv*(mu-mb)^2 ; q = sum iv*mu^2
#pragma unroll
        for (int nt = 0; nt < 2; ++nt) {
            const int col = col0 + wn * 32 + nt * 16 + lr;
            const float bmc = bm[col], bvc = bv[col];
            float c1 = 0.f, c2 = 0.f, c3 = 0.f, c4 = 0.f;
#pragma unroll
            for (int mt = 0; mt < 2; ++mt) {
#pragma unroll
                for (int r = 0; r < 4; ++r) {
                    const int row = row0 + wm * 32 + mt * 16 + quad * 4 + r;
                    float mu = accm[mt][nt][r] + bmc;
                    float tv = fast_tanh(accv[mt][nt][r] + bvc);
                    float iv = __expf(-tv);
                    float mbv = mb[(size_t)row * Hn + col];
                    float d = mu - mbv;
                    pos += iv * d * d;
                    q   += iv * mu * mu;
                    c1 += mu; c2 += mu * mu; c3 += iv; c4 += iv * mu;
                }
            }
            // reduce across quads (lanes with same lr hold the same column)
            c1 += __shfl_xor(c1, 16); c1 += __shfl_xor(c1, 32);
            c2 += __shfl_xor(c2, 16); c2 += __shfl_xor(c2, 32);
            c3 += __shfl_xor(c3, 16); c3 += __shfl_xor(c3, 32);
            c4 += __shfl_xor(c4, 16); c4 += __shfl_xor(c4, 32);
            if (quad == 0) {
                atomicAdd(&cs[col], c1);
                atomicAdd(&cs2[col], c2);
                atomicAdd(&siv[col], c3);
                atomicAdd(&sivmu[col], c4);
            }
        }
        // block-reduce the two scalars
        for (int off = 32; off > 0; off >>= 1) {
            pos += __shfl_down(pos, off);
            q   += __shfl_down(q, off);
        }
        __shared__ float redP[4], redQ[4];
        if (lane == 0) { redP[w] = pos; redQ[w] = q; }
        __syncthreads();
        if (t == 0) {
            atomicAdd(&accum[0], redP[0] + redP[1] + redP[2] + redP[3]);
            atomicAdd(&accum[1], redQ[0] + redQ[1] + redQ[2] + redQ[3]);
        }
    }
}

// ---------------- tiny combine: 768 columns -> 2 scalars ----------------
__global__ void combine_kernel(const float* __restrict__ cs, const float* __restrict__ cs2,
                               const float* __restrict__ siv, const float* __restrict__ sivmu,
                               const float* __restrict__ accum, float* __restrict__ out) {
    const int h = threadIdx.x;   // 768 threads = 12 waves
    float term = siv[h] * cs2[h] - 2.0f * sivmu[h] * cs[h];
    for (int off = 32; off > 0; off >>= 1) term += __shfl_down(term, off);
    __shared__ float red[12];
    const int lane = h & 63, w = h >> 6;
    if (lane == 0) red[w] = term;
    __syncthreads();
    if (h == 0) {
        float T = 0.f;
#pragma unroll
        for (int i = 0; i < 12; ++i) T += red[i];
        float P = accum[0];            // sum iv*(mu-mb)^2
        float Q = accum[1];            // sum iv*mu^2
        float pos_sum = -0.5f * P;
        float neg_sum = -0.5f * (T * invB + Q);
        out[0] = pos_sum * invB;
        out[1] = (pos_sum - neg_sum) * invB;
    }
}

extern "C" void kernel_launch(void* const* d_in, const int* in_sizes, int n_in,
                              void* d_out, int out_size, void* d_ws, size_t ws_size,
                              hipStream_t stream) {
    const float* modal_a = (const float*)d_in[0];
    const float* modal_b = (const float*)d_in[1];
    const float* W1m = (const float*)d_in[2];
    const float* b1m = (const float*)d_in[3];
    const float* W2m = (const float*)d_in[4];
    const float* b2m = (const float*)d_in[5];
    const float* W1v = (const float*)d_in[6];
    const float* b1v = (const float*)d_in[7];
    const float* W2v = (const float*)d_in[8];
    const float* b2v = (const float*)d_in[9];
    float* out = (float*)d_out;

    char* ws = (char*)d_ws;
    constexpr size_t szAH = (size_t)Bn * Hn * 2;   // bf16 [B,H]
    constexpr size_t szW  = (size_t)Hn * Hn * 2;   // bf16 [H,H]
    short* A_bf   = (short*)(ws);
    short* h1m    = (short*)(ws + szAH);
    short* h1v    = (short*)(ws + 2 * szAH);
    short* W1m_bf = (short*)(ws + 3 * szAH);
    short* W2m_bf = (short*)(ws + 3 * szAH + szW);
    short* W1v_bf = (short*)(ws + 3 * szAH + 2 * szW);
    short* W2v_bf = (short*)(ws + 3 * szAH + 3 * szW);
    float* cs     = (float*)(ws + 3 * szAH + 4 * szW);
    float* cs2    = cs + Hn;
    float* siv    = cs + 2 * Hn;
    float* sivmu  = cs + 3 * Hn;
    float* accum  = cs + 4 * Hn;   // [0]=P [1]=Q

    // 1. fused zero + convert
    prep_kernel<<<1280, 256, 0, stream>>>(modal_a, W1m, W2m, W1v, W2v,
                                          A_bf, W1m_bf, W2m_bf, W1v_bf, W2v_bf,
                                          cs, 4 * Hn + 2);

    // 2. layer-1 branch-paired GEMM: h1m = tanh(A@W1m^T+b1m), h1v = tanh(A@W1v^T+b1v)
    dim3 grid(Bn / 64, Hn / 64);
    gemm_club<1><<<grid, 256, 0, stream>>>(A_bf, A_bf, W1m_bf, W1v_bf, b1m, b1v,
                                           h1m, h1v, nullptr,
                                           nullptr, nullptr, nullptr, nullptr, nullptr);

    // 3. layer-2 branch-paired GEMM with full CLUB epilogue (no mu/iv materialization)
    gemm_club<2><<<grid, 256, 0, stream>>>(h1m, h1v, W2m_bf, W2v_bf, b2m, b2v,
                                           nullptr, nullptr, modal_b,
                                           cs, cs2, siv, sivmu, accum);

    // 4. combine 768 columns + scalars -> outputs
    combine_kernel<<<1, 768, 0, stream>>>(cs, cs2, siv, sivmu, accum, out);
}

// Round 4
// 180.759 us; speedup vs baseline: 1.3506x; 1.0915x over previous
//
#include <hip/hip_runtime.h>
#include <math.h>

typedef float v16f __attribute__((ext_vector_type(16)));
typedef short bf16x8 __attribute__((ext_vector_type(8)));

#define AS1 __attribute__((address_space(1)))
#define AS3 __attribute__((address_space(3)))

static constexpr int Bn = 8192;   // batch
static constexpr int Hn = 768;    // hidden
static constexpr float invB = 1.0f / 8192.0f;

__device__ __forceinline__ short f32_to_bf16(float x) {
    union { float f; unsigned u; } v; v.f = x;
    unsigned r = (v.u + 0x7FFFu + ((v.u >> 16) & 1u)) >> 16;
    return (short)r;
}

// tanh(x) = 1 - 2/(exp(2x)+1)
__device__ __forceinline__ float fast_tanh(float x) {
    float xc = fminf(fmaxf(x, -15.0f), 15.0f);
    float e = __expf(2.0f * xc);
    float r = __builtin_amdgcn_rcpf(e + 1.0f);
    return 1.0f - 2.0f * r;
}

// ---------------- fused prep: zero accumulators + fp32->bf16 all 5 tensors ----------------
__global__ void prep_kernel(const float* __restrict__ A,
                            const float* __restrict__ W1m, const float* __restrict__ W2m,
                            const float* __restrict__ W1v, const float* __restrict__ W2v,
                            short* __restrict__ A_bf,
                            short* __restrict__ W1m_bf, short* __restrict__ W2m_bf,
                            short* __restrict__ W1v_bf, short* __restrict__ W2v_bf,
                            float* __restrict__ zbuf, int nzero) {
    const int tid = blockIdx.x * blockDim.x + threadIdx.x;
    if (tid < nzero) zbuf[tid] = 0.0f;
    constexpr int A4 = Bn * Hn / 4;
    constexpr int W4 = Hn * Hn / 4;
    const int total = A4 + 4 * W4;
    const int stride = gridDim.x * blockDim.x;
    for (int i = tid; i < total; i += stride) {
        const float* s; short* d; int j;
        if (i < A4) { s = A; d = A_bf; j = i; }
        else {
            int k = i - A4; int w = k / W4; j = k - w * W4;
            s = (w == 0) ? W1m : (w == 1) ? W2m : (w == 2) ? W1v : W2v;
            d = (w == 0) ? W1m_bf : (w == 1) ? W2m_bf : (w == 2) ? W1v_bf : W2v_bf;
        }
        float4 v = ((const float4*)s)[j];
        short4 o;
        o.x = f32_to_bf16(v.x); o.y = f32_to_bf16(v.y);
        o.z = f32_to_bf16(v.z); o.w = f32_to_bf16(v.w);
        ((short4*)d)[j] = o;
    }
}

// ---------------- LAYER 1: z-split 128x128 tile, 32x32x16 MFMA ----------------
// blockIdx.z = 0 -> m branch, 1 -> v branch. out = bf16(tanh(A@W^T + b))
__launch_bounds__(256, 3)
__global__ void gemm_l1(const short* __restrict__ A_g,
                        const short* __restrict__ Wm_g, const short* __restrict__ Wv_g,
                        const float* __restrict__ bm, const float* __restrict__ bv,
                        short* __restrict__ outm, short* __restrict__ outv) {
    constexpr int K = Hn;
    __shared__ __align__(16) short As[128 * 64];   // 16KB
    __shared__ __align__(16) short Ws[128 * 64];   // 16KB

    const int z = blockIdx.z;
    const short* W = z ? Wv_g : Wm_g;
    const float* bias = z ? bv : bm;
    short* out = z ? outv : outm;

    const int t = threadIdx.x;
    const int row0 = blockIdx.x * 128;
    const int col0 = blockIdx.y * 128;
    const int w = t >> 6, lane = t & 63;
    const int wm = w >> 1, wn = w & 1;    // 2x2 waves, 64x64 each
    const int lc = lane & 31, lh = lane >> 5;

    const int rt = t >> 3;                // 0..31
    const int bsrc = (t & 7) ^ (rt & 7);  // XOR-swizzled k-block source

    const short* pA[4]; const short* pW[4];
#pragma unroll
    for (int i = 0; i < 4; ++i) {
        pA[i] = A_g + (size_t)(row0 + i * 32 + rt) * K + bsrc * 8;
        pW[i] = W + (size_t)(col0 + i * 32 + rt) * K + bsrc * 8;
    }

    v16f acc[2][2] = {};

    for (int k0 = 0; k0 < K; k0 += 64) {
#pragma unroll
        for (int i = 0; i < 4; ++i) {
            __builtin_amdgcn_global_load_lds((AS1 void*)pA[i], (AS3 void*)&As[i * 2048 + t * 8], 16, 0, 0);
            __builtin_amdgcn_global_load_lds((AS1 void*)pW[i], (AS3 void*)&Ws[i * 2048 + t * 8], 16, 0, 0);
            pA[i] += 64; pW[i] += 64;
        }
        __syncthreads();
#pragma unroll
        for (int ks = 0; ks < 4; ++ks) {
            const int kb = ks * 2 + lh;
            bf16x8 af[2], bfr[2];
#pragma unroll
            for (int mt = 0; mt < 2; ++mt) {
                int m = wm * 64 + mt * 32 + lc;
                af[mt] = *(const bf16x8*)&As[m * 64 + ((kb ^ (m & 7)) << 3)];
            }
#pragma unroll
            for (int nt = 0; nt < 2; ++nt) {
                int n = wn * 64 + nt * 32 + lc;
                bfr[nt] = *(const bf16x8*)&Ws[n * 64 + ((kb ^ (n & 7)) << 3)];
            }
#pragma unroll
            for (int mt = 0; mt < 2; ++mt)
#pragma unroll
                for (int nt = 0; nt < 2; ++nt)
                    acc[mt][nt] = __builtin_amdgcn_mfma_f32_32x32x16_bf16(af[mt], bfr[nt], acc[mt][nt], 0, 0, 0);
        }
        __syncthreads();
    }

    // epilogue: 32x32 C/D layout col=lane&31, row=(reg&3)+8*(reg>>2)+4*lh
#pragma unroll
    for (int nt = 0; nt < 2; ++nt) {
        const int col = col0 + wn * 64 + nt * 32 + lc;
        const float bc = bias[col];
#pragma unroll
        for (int mt = 0; mt < 2; ++mt) {
#pragma unroll
            for (int reg = 0; reg < 16; ++reg) {
                const int row = row0 + wm * 64 + mt * 32 + (reg & 3) + 8 * (reg >> 2) + 4 * lh;
                out[(size_t)row * Hn + col] = f32_to_bf16(fast_tanh(acc[mt][nt][reg] + bc));
            }
        }
    }
}

// ---------------- LAYER 2: branch-paired 128x128 tile, full CLUB epilogue ----------------
__launch_bounds__(256, 2)
__global__ void gemm_l2(const short* __restrict__ Am_g, const short* __restrict__ Av_g,
                        const short* __restrict__ Wm_g, const short* __restrict__ Wv_g,
                        const float* __restrict__ bm, const float* __restrict__ bv,
                        const float* __restrict__ mb,
                        float* __restrict__ cs, float* __restrict__ cs2,
                        float* __restrict__ siv, float* __restrict__ sivmu,
                        float* __restrict__ accum) {
    constexpr int K = Hn;
    __shared__ __align__(16) short As_m[128 * 64];
    __shared__ __align__(16) short As_v[128 * 64];
    __shared__ __align__(16) short Ws_m[128 * 64];
    __shared__ __align__(16) short Ws_v[128 * 64];   // 64KB total

    const int t = threadIdx.x;
    const int row0 = blockIdx.x * 128;
    const int col0 = blockIdx.y * 128;
    const int w = t >> 6, lane = t & 63;
    const int wm = w >> 1, wn = w & 1;
    const int lc = lane & 31, lh = lane >> 5;

    const int rt = t >> 3;
    const int bsrc = (t & 7) ^ (rt & 7);

    const short* pAm[4]; const short* pAv[4]; const short* pWm[4]; const short* pWv[4];
#pragma unroll
    for (int i = 0; i < 4; ++i) {
        pAm[i] = Am_g + (size_t)(row0 + i * 32 + rt) * K + bsrc * 8;
        pAv[i] = Av_g + (size_t)(row0 + i * 32 + rt) * K + bsrc * 8;
        pWm[i] = Wm_g + (size_t)(col0 + i * 32 + rt) * K + bsrc * 8;
        pWv[i] = Wv_g + (size_t)(col0 + i * 32 + rt) * K + bsrc * 8;
    }

    v16f accm[2][2] = {}, accv[2][2] = {};

    for (int k0 = 0; k0 < K; k0 += 64) {
#pragma unroll
        for (int i = 0; i < 4; ++i) {
            __builtin_amdgcn_global_load_lds((AS1 void*)pAm[i], (AS3 void*)&As_m[i * 2048 + t * 8], 16, 0, 0);
            __builtin_amdgcn_global_load_lds((AS1 void*)pAv[i], (AS3 void*)&As_v[i * 2048 + t * 8], 16, 0, 0);
            __builtin_amdgcn_global_load_lds((AS1 void*)pWm[i], (AS3 void*)&Ws_m[i * 2048 + t * 8], 16, 0, 0);
            __builtin_amdgcn_global_load_lds((AS1 void*)pWv[i], (AS3 void*)&Ws_v[i * 2048 + t * 8], 16, 0, 0);
            pAm[i] += 64; pAv[i] += 64; pWm[i] += 64; pWv[i] += 64;
        }
        __syncthreads();
#pragma unroll
        for (int ks = 0; ks < 4; ++ks) {
            const int kb = ks * 2 + lh;
            bf16x8 am[2], av[2], bmf[2], bvf[2];
#pragma unroll
            for (int mt = 0; mt < 2; ++mt) {
                int m = wm * 64 + mt * 32 + lc;
                int off = m * 64 + ((kb ^ (m & 7)) << 3);
                am[mt] = *(const bf16x8*)&As_m[off];
                av[mt] = *(const bf16x8*)&As_v[off];
            }
#pragma unroll
            for (int nt = 0; nt < 2; ++nt) {
                int n = wn * 64 + nt * 32 + lc;
                int off = n * 64 + ((kb ^ (n & 7)) << 3);
                bmf[nt] = *(const bf16x8*)&Ws_m[off];
                bvf[nt] = *(const bf16x8*)&Ws_v[off];
            }
#pragma unroll
            for (int mt = 0; mt < 2; ++mt)
#pragma unroll
                for (int nt = 0; nt < 2; ++nt) {
                    accm[mt][nt] = __builtin_amdgcn_mfma_f32_32x32x16_bf16(am[mt], bmf[nt], accm[mt][nt], 0, 0, 0);
                    accv[mt][nt] = __builtin_amdgcn_mfma_f32_32x32x16_bf16(av[mt], bvf[nt], accv[mt][nt], 0, 0, 0);
                }
        }
        __syncthreads();
    }

    // ---------------- CLUB epilogue ----------------
    float pos = 0.f, q = 0.f;   // pos = sum iv*(mu-mb)^2 ; q = sum iv*mu^2
#pragma unroll
    for (int nt = 0; nt < 2; ++nt) {
        const int col = col0 + wn * 64 + nt * 32 + lc;
        const float bmc = bm[col], bvc = bv[col];
        float c1 = 0.f, c2 = 0.f, c3 = 0.f, c4 = 0.f;
#pragma unroll
        for (int mt = 0; mt < 2; ++mt) {
#pragma unroll
            for (int reg = 0; reg < 16; ++reg) {
                const int row = row0 + wm * 64 + mt * 32 + (reg & 3) + 8 * (reg >> 2) + 4 * lh;
                float mu = accm[mt][nt][reg] + bmc;
                float tv = fast_tanh(accv[mt][nt][reg] + bvc);
                float iv = __expf(-tv);
                float mbv = mb[(size_t)row * Hn + col];
                float d = mu - mbv;
                pos += iv * d * d;
                q   += iv * mu * mu;
                c1 += mu; c2 += mu * mu; c3 += iv; c4 += iv * mu;
            }
        }
        // merge half-waves (lanes l, l^32 share col)
        c1 += __shfl_xor(c1, 32); c2 += __shfl_xor(c2, 32);
        c3 += __shfl_xor(c3, 32); c4 += __shfl_xor(c4, 32);
        if (lh == 0) {
            atomicAdd(&cs[col], c1);
            atomicAdd(&cs2[col], c2);
            atomicAdd(&siv[col], c3);
            atomicAdd(&sivmu[col], c4);
        }
    }
    // block-reduce the two scalars
    for (int off = 32; off > 0; off >>= 1) {
        pos += __shfl_down(pos, off);
        q   += __shfl_down(q, off);
    }
    __shared__ float redP[4], redQ[4];
    if (lane == 0) { redP[w] = pos; redQ[w] = q; }
    __syncthreads();
    if (t == 0) {
        atomicAdd(&accum[0], redP[0] + redP[1] + redP[2] + redP[3]);
        atomicAdd(&accum[1], redQ[0] + redQ[1] + redQ[2] + redQ[3]);
    }
}

// ---------------- tiny combine: 768 columns -> 2 scalars ----------------
__global__ void combine_kernel(const float* __restrict__ cs, const float* __restrict__ cs2,
                               const float* __restrict__ siv, const float* __restrict__ sivmu,
                               const float* __restrict__ accum, float* __restrict__ out) {
    const int h = threadIdx.x;   // 768 threads
    float term = siv[h] * cs2[h] - 2.0f * sivmu[h] * cs[h];
    for (int off = 32; off > 0; off >>= 1) term += __shfl_down(term, off);
    __shared__ float red[12];
    const int lane = h & 63, w = h >> 6;
    if (lane == 0) red[w] = term;
    __syncthreads();
    if (h == 0) {
        float T = 0.f;
#pragma unroll
        for (int i = 0; i < 12; ++i) T += red[i];
        float P = accum[0];
        float Q = accum[1];
        float pos_sum = -0.5f * P;
        float neg_sum = -0.5f * (T * invB + Q);
        out[0] = pos_sum * invB;
        out[1] = (pos_sum - neg_sum) * invB;
    }
}

extern "C" void kernel_launch(void* const* d_in, const int* in_sizes, int n_in,
                              void* d_out, int out_size, void* d_ws, size_t ws_size,
                              hipStream_t stream) {
    const float* modal_a = (const float*)d_in[0];
    const float* modal_b = (const float*)d_in[1];
    const float* W1m = (const float*)d_in[2];
    const float* b1m = (const float*)d_in[3];
    const float* W2m = (const float*)d_in[4];
    const float* b2m = (const float*)d_in[5];
    const float* W1v = (const float*)d_in[6];
    const float* b1v = (const float*)d_in[7];
    const float* W2v = (const float*)d_in[8];
    const float* b2v = (const float*)d_in[9];
    float* out = (float*)d_out;

    char* ws = (char*)d_ws;
    constexpr size_t szAH = (size_t)Bn * Hn * 2;   // bf16 [B,H]
    constexpr size_t szW  = (size_t)Hn * Hn * 2;   // bf16 [H,H]
    short* A_bf   = (short*)(ws);
    short* h1m    = (short*)(ws + szAH);
    short* h1v    = (short*)(ws + 2 * szAH);
    short* W1m_bf = (short*)(ws + 3 * szAH);
    short* W2m_bf = (short*)(ws + 3 * szAH + szW);
    short* W1v_bf = (short*)(ws + 3 * szAH + 2 * szW);
    short* W2v_bf = (short*)(ws + 3 * szAH + 3 * szW);
    float* cs     = (float*)(ws + 3 * szAH + 4 * szW);
    float* cs2    = cs + Hn;
    float* siv    = cs + 2 * Hn;
    float* sivmu  = cs + 3 * Hn;
    float* accum  = cs + 4 * Hn;   // [0]=P [1]=Q

    // 1. fused zero + convert
    prep_kernel<<<1280, 256, 0, stream>>>(modal_a, W1m, W2m, W1v, W2v,
                                          A_bf, W1m_bf, W2m_bf, W1v_bf, W2v_bf,
                                          cs, 4 * Hn + 2);

    // 2. layer-1 z-split GEMM: h1{m,v} = tanh(A@W1{m,v}^T + b1{m,v})
    gemm_l1<<<dim3(Bn / 128, Hn / 128, 2), 256, 0, stream>>>(
        A_bf, W1m_bf, W1v_bf, b1m, b1v, h1m, h1v);

    // 3. layer-2 branch-paired GEMM with full CLUB epilogue
    gemm_l2<<<dim3(Bn / 128, Hn / 128), 256, 0, stream>>>(
        h1m, h1v, W2m_bf, W2v_bf, b2m, b2v, modal_b,
        cs, cs2, siv, sivmu, accum);

    // 4. combine
    combine_kernel<<<1, 768, 0, stream>>>(cs, cs2, siv, sivmu, accum, out);
}